// Round 5
// baseline (275.010 us; speedup 1.0000x reference)
//
#include <hip/hip_runtime.h>
#include <math.h>

typedef _Float16 f16;
typedef f16 half8 __attribute__((ext_vector_type(8)));
typedef float f32x4 __attribute__((ext_vector_type(4)));

// Problem sizes: B=4, T=2048, G=8, D=128, V=1024
#define BT 8192
#define NG 8
#define ND 128
#define NV 1024
#define MARGIN 0.02f

// d_out layout (float32): ids[65536] | quantized_st[8388608] | 3 losses
#define OUT_IDS 0
#define OUT_Q   65536
#define OUT_L   (65536 + 8388608)
// xh/xl (fp16, g-blocked) parked in d_out (33.6 MB of 33.8 MB), consumed by
// mfma_gemm BEFORE reduce_flag/gather overwrite ids/Q regions.

// ws float offsets (~13.5 MB total, same budget as R4 which fit)
#define OFF_C2    0          // c2 original layout [v*8+g]      (8192)
#define OFF_C2B   8192       // c2 blocked [g*NV+v]             (8192)
#define OFF_X2    16384      // x2 [n*8+g]                      (65536)
#define OFF_IDS   81920      // ids int                         (65536)
#define OFF_LOSS  147456     // per-token loss                  (8192)
#define OFF_CNT   155648     // flag count                      (8)
#define OFF_FLAGS 155656     // flag list                       (65536)
#define OFF_CBH   221192     // cbh fp16 blocked                (524288 floats)
#define OFF_CBL   745480     // cbl fp16 blocked                (524288 floats)
#define OFF_PART  1269768    // part float4 [tok*8+g][8cn]      (2097152 floats)

// ---------------------------------------------------------------------------
// prep: fused c2 (both layouts) + x2 + fp16 split-convert of x and cb
// (g-blocked rows) + cnt=0.  One thread per 128-elem row.
// x2/c2 arithmetic identical to R1 (pairwise-8 accs, mul+add, acc j = d&7).
// ---------------------------------------------------------------------------
__global__ __launch_bounds__(256) void prep_kernel(
    const float* __restrict__ x, const float* __restrict__ cb,
    f16* __restrict__ xh, f16* __restrict__ xl,
    f16* __restrict__ cbh, f16* __restrict__ cbl,
    float* __restrict__ c2a, float* __restrict__ c2b,
    float* __restrict__ x2o, int* __restrict__ cnt) {
    int idx = blockIdx.x * 256 + threadIdx.x;
    if (idx == 0) *cnt = 0;

    const float4* src;
    f16 *dh, *dl;
    if (idx < BT * NG) {                       // x row: idx = g*BT + n
        int g = idx >> 13, n = idx & 8191;
        src = (const float4*)(x + ((size_t)n * NG + g) * ND);
        dh = xh + (size_t)idx * ND;
        dl = xl + (size_t)idx * ND;
    } else {                                   // cb row: j2 = g*NV + v
        int j2 = idx - BT * NG;
        int g = j2 >> 10, v = j2 & 1023;
        src = (const float4*)(cb + ((size_t)v * NG + g) * ND);
        dh = cbh + (size_t)j2 * ND;
        dl = cbl + (size_t)j2 * ND;
    }

    float r[8];
#pragma unroll
    for (int j = 0; j < 8; ++j) r[j] = 0.0f;
#pragma unroll
    for (int i = 0; i < 16; ++i) {
        float4 a = src[2 * i], b = src[2 * i + 1];
        float v[8] = {a.x, a.y, a.z, a.w, b.x, b.y, b.z, b.w};
        half8 h, l;
#pragma unroll
        for (int j = 0; j < 8; ++j) {
            r[j] = __fadd_rn(r[j], __fmul_rn(v[j], v[j]));
            f16 hh = (f16)v[j];
            h[j] = hh;
            l[j] = (f16)(v[j] - (float)hh);
        }
        *(half8*)(dh + i * 8) = h;
        *(half8*)(dl + i * 8) = l;
    }
    float s = __fadd_rn(
        __fadd_rn(__fadd_rn(r[0], r[1]), __fadd_rn(r[2], r[3])),
        __fadd_rn(__fadd_rn(r[4], r[5]), __fadd_rn(r[6], r[7])));

    if (idx < BT * NG) {
        int g = idx >> 13, n = idx & 8191;
        x2o[n * NG + g] = s;
    } else {
        int j2 = idx - BT * NG;
        int g = j2 >> 10, v = j2 & 1023;
        c2a[v * NG + g] = s;     // recheck layout
        c2b[j2] = s;             // gemm layout
    }
}

// ---------------------------------------------------------------------------
// MFMA distance GEMM + per-tile argmin/flag-count.
// Grid 512 = (cn,g,tmc): b = cn*64 + g*8 + tmc (A-chunk sharers on one XCD).
// Block: stage B-tile (128 codes, h+l, swizzled) ONCE, loop 8 token tiles.
// Wave = 32 tokens x 128 codes -> argmin completes in-wave, 1 barrier/block.
// s = xh*ch + xh*cl + xl*ch (3 chained mfma_f32_16x16x32_f16).
// d' = c2 - 2s (x2 dropped: cancels in argmin and gaps); near-ties flagged
// via count of codes < d1+MARGIN -> exact recheck. Sound for any fp16 error.
// ---------------------------------------------------------------------------
__global__ __launch_bounds__(256, 2) void mfma_gemm(
    const f16* __restrict__ xhb, const f16* __restrict__ xlb,
    const f16* __restrict__ cbhb, const f16* __restrict__ cblb,
    const float* __restrict__ c2b, float4* __restrict__ part) {
    __shared__ f16 Bh[128 * 128];
    __shared__ f16 Bl[128 * 128];

    const int tid = threadIdx.x;
    const int b = blockIdx.x;
    const int cn = b >> 6;
    const int g = (b >> 3) & 7;
    const int tmc = b & 7;
    const int vb0 = cn * 128;
    const int lane = tid & 63;
    const int w = tid >> 6;
    const int l15 = lane & 15, l4 = lane >> 4;

    // stage B tiles (swizzled: col16 ^= row&7)
#pragma unroll
    for (int i = 0; i < 8; ++i) {
        int s = i * 256 + tid;
        int row = s >> 4, k16 = s & 15;
        size_t gb = ((size_t)g * NV + vb0 + row) * ND + k16 * 8;
        int lo = row * 128 + ((k16 ^ (row & 7)) << 3);
        *(half8*)&Bh[lo] = *(const half8*)(cbhb + gb);
        *(half8*)&Bl[lo] = *(const half8*)(cblb + gb);
    }

    float c2r[8];
    int codes[8];
#pragma unroll
    for (int tj = 0; tj < 8; ++tj) {
        c2r[tj] = c2b[(size_t)g * NV + vb0 + tj * 16 + l15];
        codes[tj] = vb0 + tj * 16 + l15;
    }

    __syncthreads();

    const size_t abase = ((size_t)g * BT + tmc * 1024 + w * 32 + l15) * ND + l4 * 8;

#pragma unroll 1
    for (int t = 0; t < 8; ++t) {
        const f16* ah_p = xhb + abase + (size_t)t * 128 * ND;
        const f16* al_p = xlb + abase + (size_t)t * 128 * ND;
        half8 ah[4][2], al[4][2];
#pragma unroll
        for (int kk = 0; kk < 4; ++kk)
#pragma unroll
            for (int ti = 0; ti < 2; ++ti) {
                ah[kk][ti] = *(const half8*)(ah_p + ti * 16 * ND + kk * 32);
                al[kk][ti] = *(const half8*)(al_p + ti * 16 * ND + kk * 32);
            }

        f32x4 acc[2][8];
#pragma unroll
        for (int ti = 0; ti < 2; ++ti)
#pragma unroll
            for (int tj = 0; tj < 8; ++tj) acc[ti][tj] = (f32x4){0.f, 0.f, 0.f, 0.f};

#pragma unroll
        for (int kk = 0; kk < 4; ++kk) {
            half8 bh[8], bl[8];
#pragma unroll
            for (int tj = 0; tj < 8; ++tj) {
                int row = tj * 16 + l15;
                int off = row * 128 + (((kk * 4 + l4) ^ (row & 7)) << 3);
                bh[tj] = *(half8*)&Bh[off];
                bl[tj] = *(half8*)&Bl[off];
            }
#pragma unroll
            for (int ti = 0; ti < 2; ++ti)
#pragma unroll
                for (int tj = 0; tj < 8; ++tj)
                    acc[ti][tj] = __builtin_amdgcn_mfma_f32_16x16x32_f16(
                        ah[kk][ti], bh[tj], acc[ti][tj], 0, 0, 0);
#pragma unroll
            for (int ti = 0; ti < 2; ++ti)
#pragma unroll
                for (int tj = 0; tj < 8; ++tj)
                    acc[ti][tj] = __builtin_amdgcn_mfma_f32_16x16x32_f16(
                        ah[kk][ti], bl[tj], acc[ti][tj], 0, 0, 0);
#pragma unroll
            for (int ti = 0; ti < 2; ++ti)
#pragma unroll
                for (int tj = 0; tj < 8; ++tj)
                    acc[ti][tj] = __builtin_amdgcn_mfma_f32_16x16x32_f16(
                        al[kk][ti], bh[tj], acc[ti][tj], 0, 0, 0);
        }

        // epilogue: d' = c2 - 2s; in-wave argmin + margin count
#pragma unroll
        for (int ti = 0; ti < 2; ++ti) {
#pragma unroll
            for (int r = 0; r < 4; ++r) {
                float d[8];
#pragma unroll
                for (int tj = 0; tj < 8; ++tj)
                    d[tj] = fmaf(-2.0f, acc[ti][tj][r], c2r[tj]);
                float d1 = d[0];
                int id = codes[0];
#pragma unroll
                for (int tj = 1; tj < 8; ++tj)
                    if (d[tj] < d1) { d1 = d[tj]; id = codes[tj]; }
#pragma unroll
                for (int m = 1; m < 16; m <<= 1) {
                    float od = __shfl_xor(d1, m);
                    int oid = __shfl_xor(id, m);
                    if (od < d1) { d1 = od; id = oid; }
                }
                float thr = d1 + MARGIN;
                int cl = 0;
#pragma unroll
                for (int tj = 0; tj < 8; ++tj) cl += (d[tj] < thr) ? 1 : 0;
#pragma unroll
                for (int m = 1; m < 16; m <<= 1) cl += __shfl_xor(cl, m);
                if (l15 == 0) {
                    int tok = tmc * 1024 + t * 128 + w * 32 + ti * 16 + l4 * 4 + r;
                    part[((size_t)tok * NG + g) * 8 + cn] =
                        make_float4(d1, __int_as_float(id), (float)cl, 0.f);
                }
            }
        }
    }
}

// ---------------------------------------------------------------------------
// merge 8 code-tile partials; flag if winner-tile count>=2 (in-tile near-tie)
// or second tile-min within MARGIN (cross-tile near-tie).
// ---------------------------------------------------------------------------
__global__ __launch_bounds__(256) void reduce_flag(
    const float4* __restrict__ part, const int* __restrict__ pad,
    int* __restrict__ ws_ids, float* __restrict__ out_ids,
    int* __restrict__ cnt, int* __restrict__ flags) {
    int idx = blockIdx.x * 256 + threadIdx.x;
    const float4* p = part + (size_t)idx * 8;
    float4 a = p[0];
    float d1 = a.x, wcnt = a.z, d2t = INFINITY;
    int id = __float_as_int(a.y);
#pragma unroll
    for (int s = 1; s < 8; ++s) {
        float4 c = p[s];
        if (c.x < d1) { d2t = d1; d1 = c.x; id = __float_as_int(c.y); wcnt = c.z; }
        else d2t = fminf(d2t, c.x);
    }
    ws_ids[idx] = id;
    out_ids[idx] = pad[idx >> 3] ? -1.0f : (float)id;
    if (wcnt >= 2.0f || d2t - d1 < MARGIN) {
        int pos = atomicAdd(cnt, 1);
        flags[pos] = idx;
    }
}

// ---------------------------------------------------------------------------
// exact fp32 recheck for flagged (token,g): R1-identical arithmetic.
// ---------------------------------------------------------------------------
__global__ __launch_bounds__(256, 1) void recheck(
    const float* __restrict__ x, const int* __restrict__ pad,
    const float* __restrict__ cb, const float* __restrict__ c2w,
    const float* __restrict__ x2w, const int* __restrict__ cnt,
    const int* __restrict__ flags, int* __restrict__ ws_ids,
    float* __restrict__ out_ids) {
    const int lane = threadIdx.x & 63;
    const int wid = (blockIdx.x * 256 + threadIdx.x) >> 6;
    const int nw = gridDim.x * 4;
    const int n_f = cnt[0];
    for (int f = wid; f < n_f; f += nw) {
        int idx = flags[f];
        int g = idx & 7;
        const float4* xr = (const float4*)(x + (size_t)idx * ND);
        float4 xv[32];
#pragma unroll
        for (int i = 0; i < 32; ++i) xv[i] = xr[i];
        float x2v = x2w[idx];
        float best = INFINITY;
        int bid = 0;
        for (int j = 0; j < 16; ++j) {
            int c = lane + 64 * j;
            const float4* cr = (const float4*)(cb + ((size_t)c * NG + g) * ND);
            float s = 0.f;
#pragma unroll
            for (int i = 0; i < 32; ++i) {
                float4 q = cr[i];
                s = fmaf(xv[i].x, q.x, s);
                s = fmaf(xv[i].y, q.y, s);
                s = fmaf(xv[i].z, q.z, s);
                s = fmaf(xv[i].w, q.w, s);
            }
            float d = __fadd_rn(__fsub_rn(x2v, __fmul_rn(2.0f, s)),
                                c2w[(size_t)c * NG + g]);
            if (d < best) { best = d; bid = c; }
        }
#pragma unroll
        for (int m = 1; m < 64; m <<= 1) {
            float od = __shfl_xor(best, m);
            int ob = __shfl_xor(bid, m);
            if (od < best || (od == best && ob < bid)) { best = od; bid = ob; }
        }
        if (lane == 0) {
            ws_ids[idx] = bid;
            out_ids[idx] = pad[idx >> 3] ? -1.0f : (float)bid;
        }
    }
}

// ---------------------------------------------------------------------------
// gather quantized (masked), write quantized_st, per-token loss partial
// ---------------------------------------------------------------------------
__global__ __launch_bounds__(256) void gather_kernel(
    const float* __restrict__ x, const int* __restrict__ pad,
    const float* __restrict__ cb, const int* __restrict__ ws_ids,
    float* __restrict__ out_q, float* __restrict__ ws_loss) {
    const int n = blockIdx.x;
    const int tid = threadIdx.x;
    const int g = tid >> 5;
    const int d4 = tid & 31;
    const int p = pad[n];

    float4 q = make_float4(0.f, 0.f, 0.f, 0.f);
    float s = 0.f;
    if (!p) {
        int id = ws_ids[n * NG + g];
        q = ((const float4*)(cb + ((size_t)id * NG + g) * ND))[d4];
        float4 a = ((const float4*)(x + (size_t)n * (NG * ND)))[tid];
        float e0 = q.x - a.x, e1 = q.y - a.y, e2 = q.z - a.z, e3 = q.w - a.w;
        s = e0 * e0 + e1 * e1 + e2 * e2 + e3 * e3;
    }
    ((float4*)(out_q + (size_t)n * (NG * ND)))[tid] = q;

    for (int off = 32; off > 0; off >>= 1) s += __shfl_down(s, off);
    __shared__ float red[4];
    int w = tid >> 6, lane = tid & 63;
    if (lane == 0) red[w] = s;
    __syncthreads();
    if (tid == 0) ws_loss[n] = (red[0] + red[1]) + (red[2] + red[3]);
}

// ---------------------------------------------------------------------------
__global__ __launch_bounds__(256) void final_kernel(
    const int* __restrict__ pad, const float* __restrict__ ws_loss,
    float* __restrict__ out_l) {
    __shared__ float sr[256];
    __shared__ int mr[256];
    const int tid = threadIdx.x;
    float s = 0.f;
    int m = 0;
    for (int i = tid; i < BT; i += 256) {
        s += ws_loss[i];
        m += 1 - pad[i];
    }
    sr[tid] = s;
    mr[tid] = m;
    __syncthreads();
    for (int st = 128; st > 0; st >>= 1) {
        if (tid < st) { sr[tid] += sr[tid + st]; mr[tid] += mr[tid + st]; }
        __syncthreads();
    }
    if (tid == 0) {
        float k = sr[0] / (float)mr[0];
        out_l[0] = k;
        out_l[1] = k;
        out_l[2] = k + k;
    }
}

// ---------------------------------------------------------------------------
extern "C" void kernel_launch(void* const* d_in, const int* in_sizes, int n_in,
                              void* d_out, int out_size, void* d_ws, size_t ws_size,
                              hipStream_t stream) {
    const float* x = (const float*)d_in[0];
    const int* pad = (const int*)d_in[1];
    const float* cb = (const float*)d_in[2];
    float* out = (float*)d_out;
    float* ws = (float*)d_ws;

    float* ws_c2 = ws + OFF_C2;
    float* ws_c2b = ws + OFF_C2B;
    float* ws_x2 = ws + OFF_X2;
    int* ws_ids = (int*)(ws + OFF_IDS);
    float* ws_loss = ws + OFF_LOSS;
    int* ws_cnt = (int*)(ws + OFF_CNT);
    int* ws_flags = (int*)(ws + OFF_FLAGS);
    f16* cbh = (f16*)(ws + OFF_CBH);
    f16* cbl = (f16*)(ws + OFF_CBL);
    float4* part = (float4*)(ws + OFF_PART);
    f16* xh = (f16*)out;                       // parked in d_out
    f16* xl = xh + (size_t)BT * NG * ND;

    prep_kernel<<<(BT * NG + NV * NG) / 256, 256, 0, stream>>>(
        x, cb, xh, xl, cbh, cbl, ws_c2, ws_c2b, ws_x2, ws_cnt);
    mfma_gemm<<<512, 256, 0, stream>>>(xh, xl, cbh, cbl, ws_c2b, part);
    reduce_flag<<<BT * NG / 256, 256, 0, stream>>>(part, pad, ws_ids,
                                                   out + OUT_IDS, ws_cnt, ws_flags);
    recheck<<<256, 256, 0, stream>>>(x, pad, cb, ws_c2, ws_x2, ws_cnt, ws_flags,
                                     ws_ids, out + OUT_IDS);
    gather_kernel<<<BT, 256, 0, stream>>>(x, pad, cb, ws_ids, out + OUT_Q, ws_loss);
    final_kernel<<<1, 256, 0, stream>>>(pad, ws_loss, out + OUT_L);
}